// Round 8
// baseline (36.386 us; speedup 1.0000x reference)
//
#include <hip/hip_runtime.h>
#include <math.h>

#define N_IMG 64
#define H_IMG 512
#define W_IMG 512
#define EPSF 1e-6f
#define LN2F 0.69314718055994530942f

#define BPI 8                        // blocks per image: 64-row bands (= one patch row)
#define NBLK (N_IMG * BPI)           // 512 blocks
#define NT 8                         // 8-row tiles per band
#define WSSTRIDE 20
// slot: [0]=bce_log2_sum, [1]=fd_diff, [2]=fd_cnt, [3..10]=patch_d[8], [11..18]=patch_cnt[8]

__device__ __forceinline__ float wave_reduce_add(float v) {
#pragma unroll
    for (int off = 32; off > 0; off >>= 1)
        v += __shfl_down(v, off, 64);
    return v;  // valid in lane 0
}

__global__ __launch_bounds__(256, 2) void loss_main(
    const float* __restrict__ pred, const float* __restrict__ gt,
    float* __restrict__ ws)
{
    // [0..8191]: pred tile bufs (2 x 8x512), [8192..16383]: gt tile bufs. 64 KB.
    __shared__ float smem[16384];

    const int b    = blockIdx.x;
    const int n    = b >> 3;           // image
    const int prow = b & 7;            // 64-row band == patch row
    const int tid  = threadIdx.x;
    const int w    = tid >> 6;         // wave 0..3
    const int lane = tid & 63;
    const int cr   = tid >> 7;         // cell-row within 8-row tile (0..1)
    const int cc   = tid & 127;        // cell-col (4-float cells)

    const size_t band = ((size_t)n * H_IMG + (size_t)prow * 64) * W_IMG;

    // async-stage tile T (8 rows = 16 KB/tensor) into buffer BF.
    // LDS dst = wave-uniform base + lane*16B (linear layout, guide §5).
#define STAGE(T, BF) do {                                                        \
        const float* gp_ = pred + band + (size_t)(T) * 8 * W_IMG + tid * 4;      \
        const float* gg_ = gt   + band + (size_t)(T) * 8 * W_IMG + tid * 4;      \
        float* lp_ = smem + (BF) * 4096 + tid * 4;                               \
        float* lg_ = smem + 8192 + (BF) * 4096 + tid * 4;                        \
        _Pragma("unroll")                                                        \
        for (int i_ = 0; i_ < 4; ++i_) {                                         \
            __builtin_amdgcn_global_load_lds(                                    \
                (const __attribute__((address_space(1))) void*)(gp_ + i_ * 1024),\
                (__attribute__((address_space(3))) void*)(uintptr_t)(lp_ + i_ * 1024), \
                16, 0, 0);                                                       \
            __builtin_amdgcn_global_load_lds(                                    \
                (const __attribute__((address_space(1))) void*)(gg_ + i_ * 1024),\
                (__attribute__((address_space(3))) void*)(uintptr_t)(lg_ + i_ * 1024), \
                16, 0, 0);                                                       \
        }                                                                        \
    } while (0)

    STAGE(0, 0);

    float bce = 0.f, fdd = 0.f, fdc = 0.f, pdacc = 0.f, ctacc = 0.f;

    for (int t = 0; t < NT; ++t) {
        const int bf = t & 1;
        // issue next tile's loads BEFORE computing current (they stay in
        // flight across the raw barriers; never drain vmcnt to 0 mid-loop)
        if (t < NT - 1) {
            STAGE(t + 1, bf ^ 1);
            asm volatile("s_waitcnt vmcnt(8)" ::: "memory");  // current tile landed
        } else {
            asm volatile("s_waitcnt vmcnt(0)" ::: "memory");
        }
        __builtin_amdgcn_s_barrier();     // all waves' current tile visible

        const float* lp = smem + bf * 4096 + cr * 2048 + cc * 4;
        const float* lg = smem + 8192 + bf * 4096 + cr * 2048 + cc * 4;
        const float4 P0 = *(const float4*)(lp);
        const float4 P1 = *(const float4*)(lp + 512);
        const float4 P2 = *(const float4*)(lp + 1024);
        const float4 P3 = *(const float4*)(lp + 1536);
        const float4 G0 = *(const float4*)(lg);
        const float4 G1 = *(const float4*)(lg + 512);
        const float4 G2 = *(const float4*)(lg + 1024);
        const float4 G3 = *(const float4*)(lg + 1536);

        const float pv[16] = {P0.x,P0.y,P0.z,P0.w, P1.x,P1.y,P1.z,P1.w,
                              P2.x,P2.y,P2.z,P2.w, P3.x,P3.y,P3.z,P3.w};
        const float gv[16] = {G0.x,G0.y,G0.z,G0.w, G1.x,G1.y,G1.z,G1.w,
                              G2.x,G2.y,G2.z,G2.w, G3.x,G3.y,G3.z,G3.w};
        float ssum = 0.f, gsum = 0.f, pdsum = 0.f;
#pragma unroll
        for (int i = 0; i < 16; ++i) {
            const float p = pv[i], g = gv[i];
            // gt exactly 0/1: g*ln(p)+(1-g)*ln(1-p) == ln(g ? p : 1-p); keep log2
            bce += __log2f(g > 0.5f ? p : 1.0f - p);
            const float sig = __builtin_amdgcn_rcpf(1.0f + __expf(-p));
            pdsum += fabsf(sig - g);
            gsum  += g;
            ssum  += sig;
        }
        // fd loss: this thread's 4x4 cell of this tile
        const float m0r = ssum * 0.0625f, m1r = gsum * 0.0625f;
        const float m0 = (m0r > 0.f && m0r < 16.f) ? m0r : 0.f;
        const float m1 = (m1r > 0.f && m1r < 16.f) ? m1r : 0.f;
        fdd += fabsf(m0 - m1);
        fdc += (m1 > 0.f) ? 1.f : 0.f;
        pdacc += pdsum;
        ctacc += gsum;

        __builtin_amdgcn_s_barrier();     // all reads done before next overwrite
    }
#undef STAGE

    // ---- epilogue reductions; reuse dead LDS (buf0 pred area) as scratch ----
    float* rs_pd = smem;        // [4][4]
    float* rs_pc = smem + 16;   // [4][4]
    float* rs_s  = smem + 32;   // [4][3]

    {
        const float b0 = wave_reduce_add(bce);
        const float b1 = wave_reduce_add(fdd);
        const float b2 = wave_reduce_add(fdc);
        if (lane == 0) { rs_s[w*3+0] = b0; rs_s[w*3+1] = b1; rs_s[w*3+2] = b2; }
    }
    // patch partials: 16-lane groups share one 64-col patch column
    {
        float d = pdacc, c = ctacc;
        d += __shfl_down(d, 8, 64);  c += __shfl_down(c, 8, 64);
        d += __shfl_down(d, 4, 64);  c += __shfl_down(c, 4, 64);
        d += __shfl_down(d, 2, 64);  c += __shfl_down(c, 2, 64);
        d += __shfl_down(d, 1, 64);  c += __shfl_down(c, 1, 64);
        if ((lane & 15) == 0) {
            rs_pd[w*4 + (lane >> 4)] = d;
            rs_pc[w*4 + (lane >> 4)] = c;
        }
    }
    __syncthreads();

    float* slot = ws + (size_t)b * WSSTRIDE;
    if (tid == 0) {
        slot[0] = rs_s[0] + rs_s[3] + rs_s[6] + rs_s[9];
        slot[1] = rs_s[1] + rs_s[4] + rs_s[7] + rs_s[10];
        slot[2] = rs_s[2] + rs_s[5] + rs_s[8] + rs_s[11];
    }
    if (tid < 8) {
        // pcol p: waves (0,2) hold p<4, waves (1,3) hold p>=4
        const int wlo = (tid < 4) ? 0 : 1, idx = tid & 3;
        slot[3  + tid] = rs_pd[wlo*4 + idx] + rs_pd[(wlo+2)*4 + idx];
        slot[11 + tid] = rs_pc[wlo*4 + idx] + rs_pc[(wlo+2)*4 + idx];
    }
}

__global__ __launch_bounds__(256) void loss_finalize(
    const float* __restrict__ ws, float* __restrict__ out)
{
    __shared__ float l_a[12];
    __shared__ float l_cell[64][2];    // 8x8 patch grid: [cell][0]=dsum, [1]=cnt
    const int tid = threadIdx.x;

    // Phase A: bce / fd sums over all 512 block slots
    float a0 = 0.f, a1 = 0.f, a2 = 0.f;
    for (int b = tid; b < NBLK; b += 256) {
        const float* p = ws + (size_t)b * WSSTRIDE;
        a0 += p[0]; a1 += p[1]; a2 += p[2];
    }
    a0 = wave_reduce_add(a0);
    a1 = wave_reduce_add(a1);
    a2 = wave_reduce_add(a2);
    if ((tid & 63) == 0) {
        const int w = tid >> 6;
        l_a[w * 3 + 0] = a0; l_a[w * 3 + 1] = a1; l_a[w * 3 + 2] = a2;
    }

    // Phase B: block b = n*8 + prow holds patch row prow
    if (tid < 128) {
        const int cell = tid >> 1, sel = tid & 1;
        const int prow = cell >> 3, pcol = cell & 7;
        const int ofs = (sel ? 11 : 3) + pcol;
        float s = 0.f;
#pragma unroll 4
        for (int n = 0; n < N_IMG; ++n)
            s += ws[(size_t)(n * BPI + prow) * WSSTRIDE + ofs];
        l_cell[cell][sel] = s;
    }
    __syncthreads();

    if (tid != 0) return;

    const float Nf = (float)N_IMG;
    const float bce_sum = (l_a[0] + l_a[3] + l_a[6] + l_a[9]) * LN2F;  // log2 -> ln
    const float fd_d    = l_a[1] + l_a[4] + l_a[7] + l_a[10];
    const float fd_c    = l_a[2] + l_a[5] + l_a[8] + l_a[11];

    const float bce = -bce_sum / (float)((size_t)N_IMG * H_IMG * W_IMG);

    // fd loss
    const float cfd = fd_d / fmaxf(fd_c, EPSF);
    const float vessel = sqrtf(Nf * 512.f * cfd * cfd);
    float st2 = 0.f;
    for (int j = 9; j >= 2; --j) { const float s = exp2f((float)j); st2 += s * s; }
    const float loss_fd = vessel / sqrtf(st2) / Nf;

    // patch loss
    float total = 0.f;
    {   // ps=64: 8x8 grid
        float ts = 0.f;
        for (int i = 0; i < 64; ++i) {
            const float cc = l_cell[i][0] / fmaxf(l_cell[i][1], EPSF);
            ts += 64.f * Nf * cc * cc;
        }
        float local = sqrtf(ts) / 512.f / Nf;
        total += fminf(fmaxf(local, 0.f), 1.f);
    }
    {   // ps=128: 2x2 aggregation
        float ts = 0.f;
        for (int i = 0; i < 4; ++i) for (int j = 0; j < 4; ++j) {
            float d = 0.f, c = 0.f;
            for (int a = 0; a < 2; ++a) for (int bq = 0; bq < 2; ++bq) {
                const int idx = (2 * i + a) * 8 + (2 * j + bq);
                d += l_cell[idx][0]; c += l_cell[idx][1];
            }
            const float cc = d / fmaxf(c, EPSF);
            ts += 128.f * Nf * cc * cc;
        }
        float local = sqrtf(ts) / 512.f / Nf;
        total += fminf(fmaxf(local, 0.f), 1.f);
    }
    {   // ps=256: 4x4 aggregation
        float ts = 0.f;
        for (int i = 0; i < 2; ++i) for (int j = 0; j < 2; ++j) {
            float d = 0.f, c = 0.f;
            for (int a = 0; a < 4; ++a) for (int bq = 0; bq < 4; ++bq) {
                const int idx = (4 * i + a) * 8 + (4 * j + bq);
                d += l_cell[idx][0]; c += l_cell[idx][1];
            }
            const float cc = d / fmaxf(c, EPSF);
            ts += 256.f * Nf * cc * cc;
        }
        float local = sqrtf(ts) / 512.f / Nf;
        total += fminf(fmaxf(local, 0.f), 1.f);
    }
    const float loss_patch = total / 64.f;   // (512/64)^2

    out[0] = 1.1f * bce + 0.02f * loss_fd + 0.03f * loss_patch;
}

extern "C" void kernel_launch(void* const* d_in, const int* in_sizes, int n_in,
                              void* d_out, int out_size, void* d_ws, size_t ws_size,
                              hipStream_t stream)
{
    const float* pred = (const float*)d_in[0];
    const float* gt   = (const float*)d_in[1];
    float* ws  = (float*)d_ws;
    float* out = (float*)d_out;

    // every ws slot is fully written by loss_main each call: no memset needed
    loss_main<<<NBLK, 256, 0, stream>>>(pred, gt, ws);
    loss_finalize<<<1, 256, 0, stream>>>(ws, out);
}